// Round 4
// baseline (570.499 us; speedup 1.0000x reference)
//
#include <hip/hip_runtime.h>

static constexpr int Tn = 2000;
static constexpr int Bn = 512;
static constexpr int Cn = 29;
static constexpr int Ln = 150;
static constexpr float LOG2E_F = 1.4426950408889634f;
static constexpr float LN2_F   = 0.6931471805599453f;
static constexpr float NEGV    = -1e30f;

// workspace layout (floats)
static constexpr int WS_DEN_F = 0;                      // 512*32
static constexpr int WS_DEN_B = 512 * 32;               // 512*32
static constexpr int WS_NUM_F = 2 * 512 * 32;           // 512*160
static constexpr int WS_NUM_B = 2 * 512 * 32 + 512 * 160;

typedef float  f32x16 __attribute__((ext_vector_type(16)));
typedef __bf16 bf16x8 __attribute__((ext_vector_type(8)));
typedef unsigned int u32x4 __attribute__((ext_vector_type(4)));

#if __has_builtin(__builtin_amdgcn_exp2f)
#define FEXP2(x) __builtin_amdgcn_exp2f(x)
#else
#define FEXP2(x) exp2f(x)
#endif
#if __has_builtin(__builtin_amdgcn_logf)
#define FLOG2(x) __builtin_amdgcn_logf(x)
#else
#define FLOG2(x) log2f(x)
#endif

// log2(2^x + 2^y), safe for finite "NEG" sentinels (-1e30)
__device__ __forceinline__ float ladd2(float x, float y) {
    float m = fmaxf(x, y);
    float d = fminf(x, y) - m;   // <= 0, finite
    return m + FLOG2(1.0f + FEXP2(d));
}

__device__ __forceinline__ int exp_of(float x) {           // floor(log2(x)), x normal >0
    return ((__float_as_int(x) >> 23) & 255) - 127;
}
__device__ __forceinline__ unsigned short f2bf_rne(float x) {
    unsigned u = __float_as_uint(x);
    u += 0x7fffu + ((u >> 16) & 1u);
    return (unsigned short)(u >> 16);
}
__device__ __forceinline__ unsigned cvtpk_bf16(float lo, float hi) {
    unsigned r;
    asm("v_cvt_pk_bf16_f32 %0, %1, %2" : "=v"(r) : "v"(lo), "v"(hi));
    return r;
}
// exchange: a' = [a.lo | b.lo], b' = [a.hi | b.hi]  (32-lane halves)
__device__ __forceinline__ void xswap32(unsigned &a, unsigned &b) {
#if __has_builtin(__builtin_amdgcn_permlane32_swap)
    auto r = __builtin_amdgcn_permlane32_swap(a, b, false, false);
    a = r[0]; b = r[1];
#else
    unsigned pa = (unsigned)__shfl_xor((int)a, 32);
    unsigned pb = (unsigned)__shfl_xor((int)b, 32);
    bool hb = (threadIdx.x & 32) != 0;
    unsigned na = hb ? pb : a;
    unsigned nb = hb ? b : pa;
    a = na; b = nb;
#endif
}

// ================= DENOMINATOR: MFMA batch-column scan =================
// 1 wave = 32 batches (one group) x one direction. State W = alpha (or beta)
// in MFMA C/D layout: col=lane&31 (batch), row=(reg&3)+8*(reg>>2)+4*(lane>>5).
template<int BWD>
__device__ __forceinline__ void den_scan(const float* __restrict__ inp,
                                         const float* __restrict__ tr,
                                         float* __restrict__ ws, int grp)
{
    const int lane = threadIdx.x;
    const int col  = lane & 31;
    const int hi   = lane >> 5;
    const int b    = grp * 32 + col;
    const size_t BC = (size_t)Bn * Cn;

    // A fragments: lane holds A[row=col][k=8*hi+j] (frag1), k=16+8*hi+j (frag2).
    // fwd: A[i][j] = exp(trans[1+i][j]); bwd: A[j][i] = exp(trans[1+i][j]) (E^T).
    unsigned aw[8];
#pragma unroll
    for (int p = 0; p < 8; ++p) {
        int kb = (p >> 2) * 16 + 8 * hi + (p & 3) * 2;
        unsigned short lo = 0, hh = 0;
        if (col < Cn) {
            if (kb < Cn)
                lo = f2bf_rne(FEXP2(LOG2E_F * (BWD ? tr[(1 + kb) * Cn + col]
                                                   : tr[(1 + col) * Cn + kb])));
            if (kb + 1 < Cn)
                hh = f2bf_rne(FEXP2(LOG2E_F * (BWD ? tr[(2 + kb) * Cn + col]
                                                   : tr[(1 + col) * Cn + kb + 1])));
        }
        aw[p] = (unsigned)lo | ((unsigned)hh << 16);
    }
    const bf16x8 A1 = __builtin_bit_cast(bf16x8, u32x4{aw[0], aw[1], aw[2], aw[3]});
    const bf16x8 A2 = __builtin_bit_cast(bf16x8, u32x4{aw[4], aw[5], aw[6], aw[7]});

    // Per-lane emission rows (D-layout): reg r=4q+m -> row = m + 8q + 4hi = c.
    const float* base = inp + (size_t)b * Cn + 4 * hi;

    float pre[8][16];
    auto LD = [&](int slot, int iter) {
        int t = BWD ? (Tn - 1 - iter) : (1 + iter);
        const float* pt = base + (size_t)t * BC;
#pragma unroll
        for (int q = 0; q < 3; ++q)
#pragma unroll
            for (int m = 0; m < 4; ++m) pre[slot][4 * q + m] = pt[8 * q + m];
        pre[slot][12] = pt[24];
#pragma unroll
        for (int m = 1; m < 4; ++m) pre[slot][12 + m] = hi ? 0.f : pt[24 + m];
    };

    // init state
    float W[16];
    float Sacc = 0.f, gf = 0.f;
    if (!BWD) {
        float e0[16];
        {
            const float* pt = base;  // t = 0
#pragma unroll
            for (int q = 0; q < 3; ++q)
#pragma unroll
                for (int m = 0; m < 4; ++m) e0[4 * q + m] = pt[8 * q + m];
            e0[12] = pt[24];
#pragma unroll
            for (int m = 1; m < 4; ++m) e0[12 + m] = hi ? 0.f : pt[24 + m];
        }
#pragma unroll
        for (int r = 0; r < 16; ++r) {
            int row = (r & 3) + 8 * (r >> 2) + 4 * hi;
            float st = (row < Cn) ? tr[row] : 0.f;
            W[r] = (row < Cn) ? FEXP2(LOG2E_F * (e0[r] + st)) : 0.f;
        }
    } else {
#pragma unroll
        for (int r = 0; r < 16; ++r) {
            int row = (r & 3) + 8 * (r >> 2) + 4 * hi;
            W[r] = (row < Cn) ? 1.f : 0.f;
        }
    }

    const int steps = BWD ? 1000 : 999;
    LD(0, 0); LD(1, 1); LD(2, 2);

    for (int s = 0; s < steps; s += 8) {
#pragma unroll
        for (int u = 0; u < 8; ++u) {
            if (s + u < steps) {
                LD((u + 3) & 7, s + u + 3);   // depth-3 prefetch (t stays in range)
                if (!BWD) {
                    // B = pack(W); D = E*B; W = D o U_t (with scale fold)
                    unsigned pk[8];
#pragma unroll
                    for (int q = 0; q < 8; ++q) pk[q] = cvtpk_bf16(W[2 * q], W[2 * q + 1]);
                    xswap32(pk[0], pk[2]); xswap32(pk[1], pk[3]);
                    xswap32(pk[4], pk[6]); xswap32(pk[5], pk[7]);
                    bf16x8 B1 = __builtin_bit_cast(bf16x8, u32x4{pk[0], pk[1], pk[2], pk[3]});
                    bf16x8 B2 = __builtin_bit_cast(bf16x8, u32x4{pk[4], pk[5], pk[6], pk[7]});
                    f32x16 d;
#pragma unroll
                    for (int r = 0; r < 16; ++r) d[r] = 0.f;
                    d = __builtin_amdgcn_mfma_f32_32x32x16_bf16(A1, B1, d, 0, 0, 0);
                    d = __builtin_amdgcn_mfma_f32_32x32x16_bf16(A2, B2, d, 0, 0, 0);
#pragma unroll
                    for (int r = 0; r < 16; ++r)
                        W[r] = d[r] * FEXP2(fmaf(pre[u][r], LOG2E_F, -gf));
                } else {
                    // Wm = V o U_t (scale fold); B = pack(Wm); V = E^T * B
                    float Wm[16];
#pragma unroll
                    for (int r = 0; r < 16; ++r)
                        Wm[r] = W[r] * FEXP2(fmaf(pre[u][r], LOG2E_F, -gf));
                    unsigned pk[8];
#pragma unroll
                    for (int q = 0; q < 8; ++q) pk[q] = cvtpk_bf16(Wm[2 * q], Wm[2 * q + 1]);
                    xswap32(pk[0], pk[2]); xswap32(pk[1], pk[3]);
                    xswap32(pk[4], pk[6]); xswap32(pk[5], pk[7]);
                    bf16x8 B1 = __builtin_bit_cast(bf16x8, u32x4{pk[0], pk[1], pk[2], pk[3]});
                    bf16x8 B2 = __builtin_bit_cast(bf16x8, u32x4{pk[4], pk[5], pk[6], pk[7]});
                    f32x16 d;
#pragma unroll
                    for (int r = 0; r < 16; ++r) d[r] = 0.f;
                    d = __builtin_amdgcn_mfma_f32_32x32x16_bf16(A1, B1, d, 0, 0, 0);
                    d = __builtin_amdgcn_mfma_f32_32x32x16_bf16(A2, B2, d, 0, 0, 0);
#pragma unroll
                    for (int r = 0; r < 16; ++r) W[r] = d[r];
                }
                if (u == 0) gf = 0.f;         // scale applied exactly once
                if (u == 7) {                 // renorm: column max -> fold next step
                    float m = W[0];
#pragma unroll
                    for (int r = 1; r < 16; ++r) m = fmaxf(m, W[r]);
                    m = fmaxf(m, __shfl_xor(m, 32));
                    gf = (float)exp_of(m);
                    Sacc += gf;
                }
            }
        }
    }

    const int ofs = (BWD ? WS_DEN_B : WS_DEN_F) + b * 32;
#pragma unroll
    for (int r = 0; r < 16; ++r) {
        int row = (r & 3) + 8 * (r >> 2) + 4 * hi;
        if (row < Cn) ws[ofs + row] = FLOG2(W[r]) + Sacc;
    }
}

__global__ __launch_bounds__(64)
void asg_scan(const float* __restrict__ inp, const float* __restrict__ tr,
              const int* __restrict__ tg, float* __restrict__ ws)
{
    const int tid = threadIdx.x;
    const int bid = blockIdx.x;

    if (bid >= 1024) {
        const int d = bid - 1024;
        if (d >> 4) den_scan<1>(inp, tr, ws, d & 15);
        else        den_scan<0>(inp, tr, ws, d & 15);
        return;
    }

    // ================= NUMERATOR (round-2 log-domain form) =================
    // 1 wave = one (dir, b); lane k owns labels l = 3k..3k+2 (k < 50 active).
    const int dir = bid >> 9;
    const int b   = bid & 511;
    const int k   = tid;
    const int* tb = tg + b * Ln;

    const int l0 = 3 * k, l1 = 3 * k + 1, l2 = 3 * k + 2;
    const int t0i = (l0 < Ln) ? tb[l0] : 0;
    const int t1i = (l1 < Ln) ? tb[l1] : 0;
    const int t2i = (l2 < Ln) ? tb[l2] : 0;
    const float s0c = LOG2E_F * tr[(1 + t0i) * Cn + t0i];
    const float s1c = LOG2E_F * tr[(1 + t1i) * Cn + t1i];
    const float s2c = LOG2E_F * tr[(1 + t2i) * Cn + t2i];
    const int   p0  = (l0 >= 1 && l0 < Ln) ? tb[l0 - 1] : 0;
    const float m0c = (l0 >= 1 && l0 < Ln) ? LOG2E_F * tr[(1 + t0i) * Cn + p0] : 0.0f;
    const float m1c = (l1 < Ln) ? LOG2E_F * tr[(1 + t1i) * Cn + t0i] : 0.0f;
    const float m2c = (l2 < Ln) ? LOG2E_F * tr[(1 + t2i) * Cn + t1i] : 0.0f;

    float a0 = NEGV, a1 = NEGV, a2 = NEGV;
    if (dir == 0) {
        if (k == 0) a0 = LOG2E_F * (tr[t0i] + inp[(size_t)b * Cn + t0i]);
    } else {
        if (k == 49) a2 = 0.0f;   // beta_{T-1}[L-1] = 0
    }

    const int kk = (k < Cn) ? k : (Cn - 1);
    const float* eb = inp + (size_t)b * Cn + kk;  // lane k holds row value k
    const int t0    = dir ? (Tn - 1) : 1;
    const int dt    = dir ? -1 : 1;
    const int steps = dir ? 1000 : 999;

    float ce[8], ne[8];
#pragma unroll
    for (int u = 0; u < 8; ++u) {
        int tt = t0 + u * dt; tt = max(0, min(Tn - 1, tt));
        ce[u] = LOG2E_F * eb[(size_t)tt * (Bn * Cn)];
    }

    for (int s = 0; s < steps; s += 8) {
#pragma unroll
        for (int u = 0; u < 8; ++u) {
            int tt = t0 + (s + 8 + u) * dt; tt = max(0, min(Tn - 1, tt));
            ne[u] = LOG2E_F * eb[(size_t)tt * (Bn * Cn)];
        }
#pragma unroll
        for (int u = 0; u < 8; ++u) {
            if (s + u < steps) {
                float rv = ce[u];
                float e0  = __shfl(rv, t0i);
                float e1  = __shfl(rv, t1i);
                float eg2 = __shfl(rv, t2i);
                if (dir == 0) {
                    float sh = __shfl_up(a2, 1);
                    sh = (k == 0) ? NEGV : sh;
                    float n0 = e0  + ladd2(a0 + s0c, sh + m0c);
                    float n1 = e1  + ladd2(a1 + s1c, a0 + m1c);
                    float n2 = eg2 + ladd2(a2 + s2c, a1 + m2c);
                    a0 = n0; a1 = n1; a2 = n2;
                } else {
                    float sv0 = a0 + s0c + e0;
                    float mv0 = a0 + m0c + e0;
                    float sv1 = a1 + s1c + e1;
                    float mv1 = a1 + m1c + e1;
                    float sv2 = a2 + s2c + eg2;
                    float mv2 = a2 + m2c + eg2;
                    float mn = __shfl_down(mv0, 1);
                    mn = (k == 49) ? NEGV : mn;
                    a0 = ladd2(sv0, mv1);
                    a1 = ladd2(sv1, mv2);
                    a2 = ladd2(sv2, mn);
                }
            }
        }
#pragma unroll
        for (int u = 0; u < 8; ++u) ce[u] = ne[u];
    }
    const int base = (dir ? WS_NUM_B : WS_NUM_F) + b * 160;
    if (l0 < Ln)     ws[base + l0]     = a0;
    if (l0 + 1 < Ln) ws[base + l0 + 1] = a1;
    if (l0 + 2 < Ln) ws[base + l0 + 2] = a2;
}

__global__ __launch_bounds__(512)
void asg_combine(const float* __restrict__ ws, float* __restrict__ out)
{
    __shared__ float red[512];
    const int b = threadIdx.x;

    const float* f  = ws + WS_DEN_F + b * 32;
    const float* bk = ws + WS_DEN_B + b * 32;
    float vm = -3.0e38f;
#pragma unroll
    for (int i = 0; i < Cn; ++i) vm = fmaxf(vm, f[i] + bk[i]);
    float sum = 0.f;
#pragma unroll
    for (int i = 0; i < Cn; ++i) sum += FEXP2(f[i] + bk[i] - vm);
    float ld = vm + FLOG2(sum);

    const float* nf = ws + WS_NUM_F + b * 160;
    const float* nb = ws + WS_NUM_B + b * 160;
    float vm2 = -3.0e38f;
    for (int l = 0; l < Ln; ++l) vm2 = fmaxf(vm2, nf[l] + nb[l]);
    float sum2 = 0.f;
    for (int l = 0; l < Ln; ++l) sum2 += FEXP2(nf[l] + nb[l] - vm2);
    float ln = vm2 + FLOG2(sum2);

    red[b] = ld - ln;
    __syncthreads();
    for (int off = 256; off > 0; off >>= 1) {
        if (b < off) red[b] += red[b + off];
        __syncthreads();
    }
    if (b == 0) out[0] = red[0] * (LN2_F / 512.0f);
}

extern "C" void kernel_launch(void* const* d_in, const int* in_sizes, int n_in,
                              void* d_out, int out_size, void* d_ws, size_t ws_size,
                              hipStream_t stream)
{
    const float* inp = (const float*)d_in[0];
    const float* tr  = (const float*)d_in[1];
    const int*   tg  = (const int*)d_in[2];
    float* out = (float*)d_out;
    float* ws  = (float*)d_ws;

    hipLaunchKernelGGL(asg_scan,    dim3(1056), dim3(64),  0, stream, inp, tr, tg, ws);
    hipLaunchKernelGGL(asg_combine, dim3(1),    dim3(512), 0, stream, ws, out);
}

// Round 5
// 503.034 us; speedup vs baseline: 1.1341x; 1.1341x over previous
//
#include <hip/hip_runtime.h>

static constexpr int Tn = 2000;
static constexpr int Bn = 512;
static constexpr int Cn = 29;
static constexpr int Ln = 150;
static constexpr float LOG2E_F = 1.4426950408889634f;
static constexpr float LN2_F   = 0.6931471805599453f;
static constexpr float NEGV    = -1e30f;

// workspace layout (floats)
static constexpr int WS_DEN_F = 0;                      // 512*32
static constexpr int WS_DEN_B = 512 * 32;               // 512*32
static constexpr int WS_NUM_F = 2 * 512 * 32;           // 512*160
static constexpr int WS_NUM_B = 2 * 512 * 32 + 512 * 160;

typedef float  f32x16 __attribute__((ext_vector_type(16)));
typedef float  f32x4  __attribute__((ext_vector_type(4)));
typedef __bf16 bf16x8 __attribute__((ext_vector_type(8)));
typedef unsigned int u32x4 __attribute__((ext_vector_type(4)));

#if __has_builtin(__builtin_amdgcn_exp2f)
#define FEXP2(x) __builtin_amdgcn_exp2f(x)
#else
#define FEXP2(x) exp2f(x)
#endif
#if __has_builtin(__builtin_amdgcn_logf)
#define FLOG2(x) __builtin_amdgcn_logf(x)
#else
#define FLOG2(x) log2f(x)
#endif

// log2(2^x + 2^y), safe for finite "NEG" sentinels (-1e30)
__device__ __forceinline__ float ladd2(float x, float y) {
    float m = fmaxf(x, y);
    float d = fminf(x, y) - m;   // <= 0, finite
    return m + FLOG2(1.0f + FEXP2(d));
}

__device__ __forceinline__ int exp_of(float x) {           // floor(log2(x)), x normal >0
    return ((__float_as_int(x) >> 23) & 255) - 127;
}
__device__ __forceinline__ unsigned short f2bf_rne(float x) {
    unsigned u = __float_as_uint(x);
    u += 0x7fffu + ((u >> 16) & 1u);
    return (unsigned short)(u >> 16);
}
__device__ __forceinline__ unsigned cvtpk_bf16(float lo, float hi) {
    unsigned r;
    asm("v_cvt_pk_bf16_f32 %0, %1, %2" : "=v"(r) : "v"(lo), "v"(hi));
    return r;
}
// exchange halves between a and b across the lane<32 / lane>=32 split
__device__ __forceinline__ void xswap32(unsigned &a, unsigned &b) {
#if __has_builtin(__builtin_amdgcn_permlane32_swap)
    auto r = __builtin_amdgcn_permlane32_swap(a, b, false, false);
    a = r[0]; b = r[1];
#else
    unsigned pa = (unsigned)__shfl_xor((int)a, 32);
    unsigned pb = (unsigned)__shfl_xor((int)b, 32);
    bool hb = (threadIdx.x & 32) != 0;
    unsigned na = hb ? pb : a;
    unsigned nb = hb ? b : pa;
    a = na; b = nb;
#endif
}

// ================= DENOMINATOR: MFMA batch-column scan =================
// 1 wave = 32 batches (one group) x one direction. State W in MFMA C/D layout:
// col=lane&31 (batch), row=(reg&3)+8*(reg>>2)+4*(lane>>5).
template<int BWD>
__device__ __forceinline__ void den_scan(const float* __restrict__ inp,
                                         const float* __restrict__ tr,
                                         float* __restrict__ ws, int grp)
{
    const int lane = threadIdx.x;
    const int col  = lane & 31;
    const int hi   = lane >> 5;
    const int b    = grp * 32 + col;
    const size_t BC = (size_t)Bn * Cn;

    // A fragments (layout validated r4: absmax=32 pass).
    unsigned aw[8];
#pragma unroll
    for (int p = 0; p < 8; ++p) {
        int kb = (p >> 2) * 16 + 8 * hi + (p & 3) * 2;
        unsigned short lo = 0, hh = 0;
        if (col < Cn) {
            if (kb < Cn)
                lo = f2bf_rne(FEXP2(LOG2E_F * (BWD ? tr[(1 + kb) * Cn + col]
                                                   : tr[(1 + col) * Cn + kb])));
            if (kb + 1 < Cn)
                hh = f2bf_rne(FEXP2(LOG2E_F * (BWD ? tr[(2 + kb) * Cn + col]
                                                   : tr[(1 + col) * Cn + kb + 1])));
        }
        aw[p] = (unsigned)lo | ((unsigned)hh << 16);
    }
    const bf16x8 A1 = __builtin_bit_cast(bf16x8, u32x4{aw[0], aw[1], aw[2], aw[3]});
    const bf16x8 A2 = __builtin_bit_cast(bf16x8, u32x4{aw[4], aw[5], aw[6], aw[7]});

    // Emission rows per lane: reg r=4q+m -> row = m + 8q + 4hi.
    const float* base = inp + (size_t)b * Cn + 4 * hi;
    const bool tailv = (hi == 0);          // r=13,14,15 valid only for hi=0

    // depth-4 float4 ring: 64 VGPRs
    f32x4 pr[4][4];
    auto LD = [&](int slot, int iter) {
        int t = BWD ? (Tn - 1 - iter) : (1 + iter);
        const float* pt = base + (size_t)t * BC;
#pragma unroll
        for (int q = 0; q < 4; ++q) {
            f32x4 v;
            __builtin_memcpy(&v, pt + 8 * q, 16);
            pr[slot][q] = v;
        }
    };

    // init state
    float W[16];
    float Sacc = 0.f, gf = 0.f;
    if (!BWD) {
        f32x4 e0[4];
#pragma unroll
        for (int q = 0; q < 4; ++q) __builtin_memcpy(&e0[q], base + 8 * q, 16);
#pragma unroll
        for (int r = 0; r < 16; ++r) {
            int row = (r & 3) + 8 * (r >> 2) + 4 * hi;
            float ev = e0[r >> 2][r & 3];
            float st = (row < Cn) ? tr[row] : 0.f;
            W[r] = (row < Cn) ? FEXP2(LOG2E_F * (ev + st)) : 0.f;
        }
    } else {
#pragma unroll
        for (int r = 0; r < 16; ++r) {
            int row = (r & 3) + 8 * (r >> 2) + 4 * hi;
            W[r] = (row < Cn) ? 1.f : 0.f;
        }
    }

    const int steps = BWD ? 1000 : 999;
    LD(0, 0); LD(1, 1); LD(2, 2); LD(3, 3);

    for (int s = 0; s < steps; s += 8) {
#pragma unroll
        for (int u = 0; u < 8; ++u) {
            if (s + u < steps) {
                const int sl = u & 3;
                // emission factors (off the MFMA chain)
                float uu[16];
#pragma unroll
                for (int r = 0; r < 16; ++r) {
                    float pe = pr[sl][r >> 2][r & 3];
                    if (r >= 13) pe = tailv ? pe : 0.0f;   // NaN-safe tail mask
                    uu[r] = FEXP2(fmaf(pe, LOG2E_F, -gf));
                }
                if (u == 0) gf = 0.f;                      // scale applied exactly once
                LD(sl, s + u + 4);                         // refill ring (depth 4)

                unsigned pk[8];
                f32x16 d;
                if (!BWD) {
                    // B = pack(W); D = E*B; W = D o U_t
#pragma unroll
                    for (int q = 0; q < 8; ++q) pk[q] = cvtpk_bf16(W[2 * q], W[2 * q + 1]);
                } else {
                    // Wm = W o U_t; B = pack(Wm); W = E^T * B
                    float Wm[16];
#pragma unroll
                    for (int r = 0; r < 16; ++r) Wm[r] = W[r] * uu[r];
#pragma unroll
                    for (int q = 0; q < 8; ++q) pk[q] = cvtpk_bf16(Wm[2 * q], Wm[2 * q + 1]);
                }
                xswap32(pk[0], pk[2]); xswap32(pk[1], pk[3]);
                xswap32(pk[4], pk[6]); xswap32(pk[5], pk[7]);
                bf16x8 B1 = __builtin_bit_cast(bf16x8, u32x4{pk[0], pk[1], pk[2], pk[3]});
                bf16x8 B2 = __builtin_bit_cast(bf16x8, u32x4{pk[4], pk[5], pk[6], pk[7]});
#pragma unroll
                for (int r = 0; r < 16; ++r) d[r] = 0.f;
                d = __builtin_amdgcn_mfma_f32_32x32x16_bf16(A1, B1, d, 0, 0, 0);
                d = __builtin_amdgcn_mfma_f32_32x32x16_bf16(A2, B2, d, 0, 0, 0);
                if (!BWD) {
#pragma unroll
                    for (int r = 0; r < 16; ++r) W[r] = d[r] * uu[r];
                } else {
#pragma unroll
                    for (int r = 0; r < 16; ++r) W[r] = d[r];
                }
                if (u == 7) {                 // renorm: column max, fold into next step
                    float m = W[0];
#pragma unroll
                    for (int r = 1; r < 16; ++r) m = fmaxf(m, W[r]);
                    m = fmaxf(m, __shfl_xor(m, 32));
                    gf = (float)exp_of(m);
                    Sacc += gf;
                }
            }
        }
    }

    const int ofs = (BWD ? WS_DEN_B : WS_DEN_F) + b * 32;
#pragma unroll
    for (int r = 0; r < 16; ++r) {
        int row = (r & 3) + 8 * (r >> 2) + 4 * hi;
        if (row < Cn) ws[ofs + row] = FLOG2(W[r]) + Sacc;
    }
}

__global__ __launch_bounds__(64)
void asg_scan(const float* __restrict__ inp, const float* __restrict__ tr,
              const int* __restrict__ tg, float* __restrict__ ws)
{
    const int tid = threadIdx.x;
    const int bid = blockIdx.x;

    if (bid < 32) {                       // den first: long pole launches early
        if (bid >> 4) den_scan<1>(inp, tr, ws, bid & 15);
        else          den_scan<0>(inp, tr, ws, bid & 15);
        return;
    }

    // ================= NUMERATOR (round-2 log-domain form, validated) =========
    const int nid = bid - 32;
    const int dir = nid >> 9;
    const int b   = nid & 511;
    const int k   = tid;
    const int* tb = tg + b * Ln;

    const int l0 = 3 * k, l1 = 3 * k + 1, l2 = 3 * k + 2;
    const int t0i = (l0 < Ln) ? tb[l0] : 0;
    const int t1i = (l1 < Ln) ? tb[l1] : 0;
    const int t2i = (l2 < Ln) ? tb[l2] : 0;
    const float s0c = LOG2E_F * tr[(1 + t0i) * Cn + t0i];
    const float s1c = LOG2E_F * tr[(1 + t1i) * Cn + t1i];
    const float s2c = LOG2E_F * tr[(1 + t2i) * Cn + t2i];
    const int   p0  = (l0 >= 1 && l0 < Ln) ? tb[l0 - 1] : 0;
    const float m0c = (l0 >= 1 && l0 < Ln) ? LOG2E_F * tr[(1 + t0i) * Cn + p0] : 0.0f;
    const float m1c = (l1 < Ln) ? LOG2E_F * tr[(1 + t1i) * Cn + t0i] : 0.0f;
    const float m2c = (l2 < Ln) ? LOG2E_F * tr[(1 + t2i) * Cn + t1i] : 0.0f;

    float a0 = NEGV, a1 = NEGV, a2 = NEGV;
    if (dir == 0) {
        if (k == 0) a0 = LOG2E_F * (tr[t0i] + inp[(size_t)b * Cn + t0i]);
    } else {
        if (k == 49) a2 = 0.0f;   // beta_{T-1}[L-1] = 0
    }

    const int kk = (k < Cn) ? k : (Cn - 1);
    const float* eb = inp + (size_t)b * Cn + kk;  // lane k holds row value k
    const int t0    = dir ? (Tn - 1) : 1;
    const int dt    = dir ? -1 : 1;
    const int steps = dir ? 1000 : 999;

    float ce[8], ne[8];
#pragma unroll
    for (int u = 0; u < 8; ++u) {
        int tt = t0 + u * dt; tt = max(0, min(Tn - 1, tt));
        ce[u] = LOG2E_F * eb[(size_t)tt * (Bn * Cn)];
    }

    for (int s = 0; s < steps; s += 8) {
#pragma unroll
        for (int u = 0; u < 8; ++u) {
            int tt = t0 + (s + 8 + u) * dt; tt = max(0, min(Tn - 1, tt));
            ne[u] = LOG2E_F * eb[(size_t)tt * (Bn * Cn)];
        }
#pragma unroll
        for (int u = 0; u < 8; ++u) {
            if (s + u < steps) {
                float rv = ce[u];
                float e0  = __shfl(rv, t0i);
                float e1  = __shfl(rv, t1i);
                float eg2 = __shfl(rv, t2i);
                if (dir == 0) {
                    float sh = __shfl_up(a2, 1);
                    sh = (k == 0) ? NEGV : sh;
                    float n0 = e0  + ladd2(a0 + s0c, sh + m0c);
                    float n1 = e1  + ladd2(a1 + s1c, a0 + m1c);
                    float n2 = eg2 + ladd2(a2 + s2c, a1 + m2c);
                    a0 = n0; a1 = n1; a2 = n2;
                } else {
                    float sv0 = a0 + s0c + e0;
                    float mv0 = a0 + m0c + e0;
                    float sv1 = a1 + s1c + e1;
                    float mv1 = a1 + m1c + e1;
                    float sv2 = a2 + s2c + eg2;
                    float mv2 = a2 + m2c + eg2;
                    float mn = __shfl_down(mv0, 1);
                    mn = (k == 49) ? NEGV : mn;
                    a0 = ladd2(sv0, mv1);
                    a1 = ladd2(sv1, mv2);
                    a2 = ladd2(sv2, mn);
                }
            }
        }
#pragma unroll
        for (int u = 0; u < 8; ++u) ce[u] = ne[u];
    }
    const int base = (dir ? WS_NUM_B : WS_NUM_F) + b * 160;
    if (l0 < Ln)     ws[base + l0]     = a0;
    if (l0 + 1 < Ln) ws[base + l0 + 1] = a1;
    if (l0 + 2 < Ln) ws[base + l0 + 2] = a2;
}

__global__ __launch_bounds__(512)
void asg_combine(const float* __restrict__ ws, float* __restrict__ out)
{
    __shared__ float red[512];
    const int b = threadIdx.x;

    const float* f  = ws + WS_DEN_F + b * 32;
    const float* bk = ws + WS_DEN_B + b * 32;
    float vm = -3.0e38f;
#pragma unroll
    for (int i = 0; i < Cn; ++i) vm = fmaxf(vm, f[i] + bk[i]);
    float sum = 0.f;
#pragma unroll
    for (int i = 0; i < Cn; ++i) sum += FEXP2(f[i] + bk[i] - vm);
    float ld = vm + FLOG2(sum);

    const float* nf = ws + WS_NUM_F + b * 160;
    const float* nb = ws + WS_NUM_B + b * 160;
    float vm2 = -3.0e38f;
    for (int l = 0; l < Ln; ++l) vm2 = fmaxf(vm2, nf[l] + nb[l]);
    float sum2 = 0.f;
    for (int l = 0; l < Ln; ++l) sum2 += FEXP2(nf[l] + nb[l] - vm2);
    float ln = vm2 + FLOG2(sum2);

    red[b] = ld - ln;
    __syncthreads();
    for (int off = 256; off > 0; off >>= 1) {
        if (b < off) red[b] += red[b + off];
        __syncthreads();
    }
    if (b == 0) out[0] = red[0] * (LN2_F / 512.0f);
}

extern "C" void kernel_launch(void* const* d_in, const int* in_sizes, int n_in,
                              void* d_out, int out_size, void* d_ws, size_t ws_size,
                              hipStream_t stream)
{
    const float* inp = (const float*)d_in[0];
    const float* tr  = (const float*)d_in[1];
    const int*   tg  = (const int*)d_in[2];
    float* out = (float*)d_out;
    float* ws  = (float*)d_ws;

    hipLaunchKernelGGL(asg_scan,    dim3(1056), dim3(64),  0, stream, inp, tr, tg, ws);
    hipLaunchKernelGGL(asg_combine, dim3(1),    dim3(512), 0, stream, ws, out);
}

// Round 6
// 273.127 us; speedup vs baseline: 2.0888x; 1.8418x over previous
//
#include <hip/hip_runtime.h>

static constexpr int Tn = 2000;
static constexpr int Bn = 512;
static constexpr int Cn = 29;
static constexpr int Ln = 150;
static constexpr float LOG2E_F = 1.4426950408889634f;
static constexpr float LN2_F   = 0.6931471805599453f;
static constexpr float NEGV    = -1e30f;

// workspace layout (floats)
static constexpr int WS_DEN_F = 0;                      // 512 (log2-domain log_den per b)
static constexpr int WS_NUM_F = 2 * 512 * 32;           // 512*160
static constexpr int WS_NUM_B = 2 * 512 * 32 + 512 * 160;

typedef float  f32x16 __attribute__((ext_vector_type(16)));
typedef float  f32x4  __attribute__((ext_vector_type(4)));
typedef __bf16 bf16x8 __attribute__((ext_vector_type(8)));
typedef unsigned int u32x4 __attribute__((ext_vector_type(4)));

#if __has_builtin(__builtin_amdgcn_exp2f)
#define FEXP2(x) __builtin_amdgcn_exp2f(x)
#else
#define FEXP2(x) exp2f(x)
#endif
#if __has_builtin(__builtin_amdgcn_logf)
#define FLOG2(x) __builtin_amdgcn_logf(x)
#else
#define FLOG2(x) log2f(x)
#endif

__device__ __forceinline__ float ladd2(float x, float y) {
    float m = fmaxf(x, y);
    float d = fminf(x, y) - m;
    return m + FLOG2(1.0f + FEXP2(d));
}
__device__ __forceinline__ int exp_of(float x) {           // floor(log2(x)), x normal >0
    return ((__float_as_int(x) >> 23) & 255) - 127;
}
__device__ __forceinline__ float pow2i(int e) {            // 2^e, e in [-126,127]
    return __int_as_float((e + 127) << 23);
}
__device__ __forceinline__ unsigned short f2bf_rne(float x) {
    unsigned u = __float_as_uint(x);
    u += 0x7fffu + ((u >> 16) & 1u);
    return (unsigned short)(u >> 16);
}
__device__ __forceinline__ unsigned cvtpk_bf16(float lo, float hi) {
    unsigned r;
    asm("v_cvt_pk_bf16_f32 %0, %1, %2" : "=v"(r) : "v"(lo), "v"(hi));
    return r;
}
__device__ __forceinline__ void xswap32(unsigned &a, unsigned &b) {
#if __has_builtin(__builtin_amdgcn_permlane32_swap)
    auto r = __builtin_amdgcn_permlane32_swap(a, b, false, false);
    a = r[0]; b = r[1];
#else
    unsigned pa = (unsigned)__shfl_xor((int)a, 32);
    unsigned pb = (unsigned)__shfl_xor((int)b, 32);
    bool hb = (threadIdx.x & 32) != 0;
    unsigned na = hb ? pb : a;
    unsigned nb = hb ? b : pa;
    a = na; b = nb;
#endif
}
// D-layout f32[16] -> B-operand fragments (validated r4/r5)
__device__ __forceinline__ void packDtoB(const float* W, bf16x8 &B1, bf16x8 &B2) {
    unsigned pk[8];
#pragma unroll
    for (int q = 0; q < 8; ++q) pk[q] = cvtpk_bf16(W[2 * q], W[2 * q + 1]);
    xswap32(pk[0], pk[2]); xswap32(pk[1], pk[3]);
    xswap32(pk[4], pk[6]); xswap32(pk[5], pk[7]);
    B1 = __builtin_bit_cast(bf16x8, u32x4{pk[0], pk[1], pk[2], pk[3]});
    B2 = __builtin_bit_cast(bf16x8, u32x4{pk[4], pk[5], pk[6], pk[7]});
}
__device__ __forceinline__ void renorm16(float* W, float &Sacc) {
    float m = W[0];
#pragma unroll
    for (int r = 1; r < 16; ++r) m = fmaxf(m, W[r]);
#pragma unroll
    for (int sh = 1; sh <= 32; sh <<= 1) m = fmaxf(m, __shfl_xor(m, sh));
    int g = exp_of(m);
    float iv = pow2i(-g);
#pragma unroll
    for (int r = 0; r < 16; ++r) W[r] *= iv;
    Sacc += (float)g;
}

__global__ __launch_bounds__(256, 4)
void asg_scan(const float* __restrict__ inp, const float* __restrict__ tr,
              const int* __restrict__ tg, float* __restrict__ ws)
{
    const int tid = threadIdx.x;
    const int bid = blockIdx.x;

    __shared__ float mats[4][32][33];
    __shared__ float uring[4][8][32];
    __shared__ float scl[4];

    if (bid < 512) {
        // ============ DENOMINATOR: segment transfer matrices ============
        // Block = batch b; wave w builds P_w = prod_{t in seg_w} (U_t E) via
        // M <- U_t * (E * M), M as B-operand, E as A-operand (validated).
        const int lane = tid & 63;
        const int wid  = tid >> 6;
        const int col  = lane & 31;
        const int hi   = lane >> 5;
        const int b    = bid;
        const size_t BC = (size_t)Bn * Cn;

        // E in bf16 A-fragments (validated r4)
        unsigned aw[8];
#pragma unroll
        for (int p = 0; p < 8; ++p) {
            int kb = (p >> 2) * 16 + 8 * hi + (p & 3) * 2;
            unsigned short lo = 0, hh = 0;
            if (col < Cn) {
                if (kb < Cn)     lo = f2bf_rne(FEXP2(LOG2E_F * tr[(1 + col) * Cn + kb]));
                if (kb + 1 < Cn) hh = f2bf_rne(FEXP2(LOG2E_F * tr[(1 + col) * Cn + kb + 1]));
            }
            aw[p] = (unsigned)lo | ((unsigned)hh << 16);
        }
        const bf16x8 A1 = __builtin_bit_cast(bf16x8, u32x4{aw[0], aw[1], aw[2], aw[3]});
        const bf16x8 A2 = __builtin_bit_cast(bf16x8, u32x4{aw[4], aw[5], aw[6], aw[7]});

        f32x16 z;
#pragma unroll
        for (int r = 0; r < 16; ++r) z[r] = 0.f;

        const int start = 1 + 500 * wid;
        const int cnt   = min(500, Tn - start);            // 500,500,500,499

        // lane -> emission row (clamped; rows>=29 are multiplied by zero rows of E)
        const float* ebase = inp + (size_t)b * Cn + min(col, Cn - 1);

        float er[8];
#pragma unroll
        for (int p = 0; p < 8; ++p)
            er[p] = ebase[(size_t)min(start + p, Tn - 1) * BC];

        if (lane < 32) {
            uring[wid][0][col] = FEXP2(LOG2E_F * er[0]);
            uring[wid][1][col] = FEXP2(LOG2E_F * er[1]);
        }

        float W[16];                                       // M in D-layout, init I
#pragma unroll
        for (int r = 0; r < 16; ++r) {
            int row = (r & 3) + 8 * (r >> 2) + 4 * hi;
            W[r] = (row == col) ? 1.0f : 0.0f;
        }
        float Sacc = 0.f;

        int s = 0;
        for (; s + 8 <= cnt; s += 8) {
#pragma unroll
            for (int u = 0; u < 8; ++u) {
                er[u] = ebase[(size_t)min(start + s + u + 8, Tn - 1) * BC];  // prefetch
                float un = FEXP2(LOG2E_F * er[(u + 2) & 7]);                 // u for step s+u+2
                if (lane < 32) uring[wid][(u + 2) & 7][col] = un;
                f32x4 uu0 = *(const f32x4*)&uring[wid][u][4 * hi];
                f32x4 uu1 = *(const f32x4*)&uring[wid][u][8 + 4 * hi];
                f32x4 uu2 = *(const f32x4*)&uring[wid][u][16 + 4 * hi];
                f32x4 uu3 = *(const f32x4*)&uring[wid][u][24 + 4 * hi];
                bf16x8 B1, B2;
                packDtoB(W, B1, B2);
                f32x16 d = __builtin_amdgcn_mfma_f32_32x32x16_bf16(A1, B1, z, 0, 0, 0);
                d = __builtin_amdgcn_mfma_f32_32x32x16_bf16(A2, B2, d, 0, 0, 0);
#pragma unroll
                for (int r = 0; r < 16; ++r) {
                    f32x4 uq = (r < 4) ? uu0 : (r < 8) ? uu1 : (r < 12) ? uu2 : uu3;
                    W[r] = d[r] * uq[r & 3];
                }
                if (u == 7) renorm16(W, Sacc);
            }
        }
        {   // tail (rem = 3 or 4); slots 0,1 already hold steps s, s+1
            const int rem = cnt - s;
            if (lane < 32) {
#pragma unroll
                for (int j = 2; j < 8; ++j)
                    if (j < rem) uring[wid][j][col] = FEXP2(LOG2E_F * er[j]);
            }
#pragma unroll
            for (int u = 0; u < 8; ++u) {
                if (u < rem) {
                    f32x4 uu0 = *(const f32x4*)&uring[wid][u][4 * hi];
                    f32x4 uu1 = *(const f32x4*)&uring[wid][u][8 + 4 * hi];
                    f32x4 uu2 = *(const f32x4*)&uring[wid][u][16 + 4 * hi];
                    f32x4 uu3 = *(const f32x4*)&uring[wid][u][24 + 4 * hi];
                    bf16x8 B1, B2;
                    packDtoB(W, B1, B2);
                    f32x16 d = __builtin_amdgcn_mfma_f32_32x32x16_bf16(A1, B1, z, 0, 0, 0);
                    d = __builtin_amdgcn_mfma_f32_32x32x16_bf16(A2, B2, d, 0, 0, 0);
#pragma unroll
                    for (int r = 0; r < 16; ++r) {
                        f32x4 uq = (r < 4) ? uu0 : (r < 8) ? uu1 : (r < 12) ? uu2 : uu3;
                        W[r] = d[r] * uq[r & 3];
                    }
                }
            }
            renorm16(W, Sacc);
        }

        // store P_w
#pragma unroll
        for (int r = 0; r < 16; ++r) {
            int row = (r & 3) + 8 * (r >> 2) + 4 * hi;
            mats[wid][row][col] = W[r];
        }
        if (lane == 0) scl[wid] = Sacc;
        __syncthreads();

        // ---- combine level 1: Q0 = P1*P0 (wave 0), Q1 = P3*P2 (wave 1) ----
        f32x16 q = z;
        float Sq = 0.f;
        if (wid < 2) {
            const float (*Lm)[33] = mats[2 * wid + 1];
            const float (*Rm)[33] = mats[2 * wid];
            unsigned lw[8];
#pragma unroll
            for (int p = 0; p < 8; ++p) {
                int kb = (p >> 2) * 16 + 8 * hi + (p & 3) * 2;
                lw[p] = (unsigned)f2bf_rne(Lm[col][kb]) |
                        ((unsigned)f2bf_rne(Lm[col][kb + 1]) << 16);
            }
            bf16x8 LA1 = __builtin_bit_cast(bf16x8, u32x4{lw[0], lw[1], lw[2], lw[3]});
            bf16x8 LA2 = __builtin_bit_cast(bf16x8, u32x4{lw[4], lw[5], lw[6], lw[7]});
            float Wr[16];
#pragma unroll
            for (int r = 0; r < 16; ++r) {
                int row = (r & 3) + 8 * (r >> 2) + 4 * hi;
                Wr[r] = Rm[row][col];
            }
            bf16x8 B1, B2;
            packDtoB(Wr, B1, B2);
            q = __builtin_amdgcn_mfma_f32_32x32x16_bf16(LA1, B1, z, 0, 0, 0);
            q = __builtin_amdgcn_mfma_f32_32x32x16_bf16(LA2, B2, q, 0, 0, 0);
            float Wq[16];
#pragma unroll
            for (int r = 0; r < 16; ++r) Wq[r] = q[r];
            float Sg = scl[2 * wid] + scl[2 * wid + 1];
            renorm16(Wq, Sg);
#pragma unroll
            for (int r = 0; r < 16; ++r) q[r] = Wq[r];
            Sq = Sg;
        }
        __syncthreads();
        if (wid == 1) {
#pragma unroll
            for (int r = 0; r < 16; ++r) {
                int row = (r & 3) + 8 * (r >> 2) + 4 * hi;
                mats[3][row][col] = q[r];
            }
            if (lane == 0) scl[3] = Sq;
        }
        __syncthreads();

        // ---- level 2 + alpha0 apply (wave 0): R = Q1*Q0; log_den ----
        if (wid == 0) {
            unsigned lw[8];
#pragma unroll
            for (int p = 0; p < 8; ++p) {
                int kb = (p >> 2) * 16 + 8 * hi + (p & 3) * 2;
                lw[p] = (unsigned)f2bf_rne(mats[3][col][kb]) |
                        ((unsigned)f2bf_rne(mats[3][col][kb + 1]) << 16);
            }
            bf16x8 LA1 = __builtin_bit_cast(bf16x8, u32x4{lw[0], lw[1], lw[2], lw[3]});
            bf16x8 LA2 = __builtin_bit_cast(bf16x8, u32x4{lw[4], lw[5], lw[6], lw[7]});
            float Wq[16];
#pragma unroll
            for (int r = 0; r < 16; ++r) Wq[r] = q[r];
            bf16x8 B1, B2;
            packDtoB(Wq, B1, B2);
            f32x16 d = __builtin_amdgcn_mfma_f32_32x32x16_bf16(LA1, B1, z, 0, 0, 0);
            d = __builtin_amdgcn_mfma_f32_32x32x16_bf16(LA2, B2, d, 0, 0, 0);
            const float Stot = Sq + scl[3];
            float a0v = 0.f;
            if (col < Cn)
                a0v = FEXP2(LOG2E_F * (inp[(size_t)b * Cn + col] + tr[col]));
            float ssum = 0.f;
#pragma unroll
            for (int r = 0; r < 16; ++r) ssum += d[r];
            float t = ssum * a0v;
#pragma unroll
            for (int sh = 1; sh <= 32; sh <<= 1) t += __shfl_xor(t, sh);
            if (lane == 0) ws[WS_DEN_F + b] = FLOG2(t) + Stot;
        }
    } else {
        // ============ NUMERATOR (round-2 validated form; 4 waves/block) ======
        const int nid = (bid - 512) * 4 + (tid >> 6);
        const int dir = nid >> 9;
        const int b   = nid & 511;
        const int k   = tid & 63;
        const int* tb = tg + b * Ln;

        const int l0 = 3 * k, l1 = 3 * k + 1, l2 = 3 * k + 2;
        const int t0i = (l0 < Ln) ? tb[l0] : 0;
        const int t1i = (l1 < Ln) ? tb[l1] : 0;
        const int t2i = (l2 < Ln) ? tb[l2] : 0;
        const float s0c = LOG2E_F * tr[(1 + t0i) * Cn + t0i];
        const float s1c = LOG2E_F * tr[(1 + t1i) * Cn + t1i];
        const float s2c = LOG2E_F * tr[(1 + t2i) * Cn + t2i];
        const int   p0  = (l0 >= 1 && l0 < Ln) ? tb[l0 - 1] : 0;
        const float m0c = (l0 >= 1 && l0 < Ln) ? LOG2E_F * tr[(1 + t0i) * Cn + p0] : 0.0f;
        const float m1c = (l1 < Ln) ? LOG2E_F * tr[(1 + t1i) * Cn + t0i] : 0.0f;
        const float m2c = (l2 < Ln) ? LOG2E_F * tr[(1 + t2i) * Cn + t1i] : 0.0f;

        float a0 = NEGV, a1 = NEGV, a2 = NEGV;
        if (dir == 0) {
            if (k == 0) a0 = LOG2E_F * (tr[t0i] + inp[(size_t)b * Cn + t0i]);
        } else {
            if (k == 49) a2 = 0.0f;
        }

        const int kk = (k < Cn) ? k : (Cn - 1);
        const float* eb = inp + (size_t)b * Cn + kk;
        const int t0    = dir ? (Tn - 1) : 1;
        const int dt    = dir ? -1 : 1;
        const int steps = dir ? 1000 : 999;

        float ce[8], ne[8];
#pragma unroll
        for (int u = 0; u < 8; ++u) {
            int tt = t0 + u * dt; tt = max(0, min(Tn - 1, tt));
            ce[u] = LOG2E_F * eb[(size_t)tt * (Bn * Cn)];
        }

        for (int s = 0; s < steps; s += 8) {
#pragma unroll
            for (int u = 0; u < 8; ++u) {
                int tt = t0 + (s + 8 + u) * dt; tt = max(0, min(Tn - 1, tt));
                ne[u] = LOG2E_F * eb[(size_t)tt * (Bn * Cn)];
            }
#pragma unroll
            for (int u = 0; u < 8; ++u) {
                if (s + u < steps) {
                    float rv = ce[u];
                    float e0  = __shfl(rv, t0i);
                    float e1  = __shfl(rv, t1i);
                    float eg2 = __shfl(rv, t2i);
                    if (dir == 0) {
                        float sh = __shfl_up(a2, 1);
                        sh = (k == 0) ? NEGV : sh;
                        float n0 = e0  + ladd2(a0 + s0c, sh + m0c);
                        float n1 = e1  + ladd2(a1 + s1c, a0 + m1c);
                        float n2 = eg2 + ladd2(a2 + s2c, a1 + m2c);
                        a0 = n0; a1 = n1; a2 = n2;
                    } else {
                        float sv0 = a0 + s0c + e0;
                        float mv0 = a0 + m0c + e0;
                        float sv1 = a1 + s1c + e1;
                        float mv1 = a1 + m1c + e1;
                        float sv2 = a2 + s2c + eg2;
                        float mv2 = a2 + m2c + eg2;
                        float mn = __shfl_down(mv0, 1);
                        mn = (k == 49) ? NEGV : mn;
                        a0 = ladd2(sv0, mv1);
                        a1 = ladd2(sv1, mv2);
                        a2 = ladd2(sv2, mn);
                    }
                }
            }
#pragma unroll
            for (int u = 0; u < 8; ++u) ce[u] = ne[u];
        }
        const int base = (dir ? WS_NUM_B : WS_NUM_F) + b * 160;
        if (l0 < Ln)     ws[base + l0]     = a0;
        if (l0 + 1 < Ln) ws[base + l0 + 1] = a1;
        if (l0 + 2 < Ln) ws[base + l0 + 2] = a2;
    }
}

__global__ __launch_bounds__(512)
void asg_combine(const float* __restrict__ ws, float* __restrict__ out)
{
    __shared__ float red[512];
    const int b = threadIdx.x;

    const float ld = ws[WS_DEN_F + b];            // log2 domain

    const float* nf = ws + WS_NUM_F + b * 160;
    const float* nb = ws + WS_NUM_B + b * 160;
    float vm2 = -3.0e38f;
    for (int l = 0; l < Ln; ++l) vm2 = fmaxf(vm2, nf[l] + nb[l]);
    float sum2 = 0.f;
    for (int l = 0; l < Ln; ++l) sum2 += FEXP2(nf[l] + nb[l] - vm2);
    float ln = vm2 + FLOG2(sum2);

    red[b] = ld - ln;
    __syncthreads();
    for (int off = 256; off > 0; off >>= 1) {
        if (b < off) red[b] += red[b + off];
        __syncthreads();
    }
    if (b == 0) out[0] = red[0] * (LN2_F / 512.0f);
}

extern "C" void kernel_launch(void* const* d_in, const int* in_sizes, int n_in,
                              void* d_out, int out_size, void* d_ws, size_t ws_size,
                              hipStream_t stream)
{
    const float* inp = (const float*)d_in[0];
    const float* tr  = (const float*)d_in[1];
    const int*   tg  = (const int*)d_in[2];
    float* out = (float*)d_out;
    float* ws  = (float*)d_ws;

    hipLaunchKernelGGL(asg_scan,    dim3(768), dim3(256), 0, stream, inp, tr, tg, ws);
    hipLaunchKernelGGL(asg_combine, dim3(1),   dim3(512), 0, stream, ws, out);
}